// Round 1
// baseline (105.621 us; speedup 1.0000x reference)
//
#include <hip/hip_runtime.h>
#include <hip/hip_bf16.h>

// Problem constants (match reference setup_inputs)
#define BB 64
#define SS 512
#define DD 1024
#define NSEG (BB * SS)   // 32768

__device__ __forceinline__ int lower_bound_dev(const int* __restrict__ a, int n, int key) {
    int lo = 0, hi = n;
    while (lo < hi) {
        int mid = (lo + hi) >> 1;
        if (a[mid] < key) lo = mid + 1; else hi = mid;
    }
    return lo;
}

__global__ __launch_bounds__(256) void seg_mean_embed_kernel(
    const int* __restrict__ tokens,
    const int* __restrict__ seg_ids,
    const float* __restrict__ emb,      // [V, D]
    const float* __restrict__ pos,      // [S, D]
    float* __restrict__ out,            // [B*S, D]
    int T)
{
    const int seg = blockIdx.x;                 // 0 .. NSEG-1
    // Wave-uniform binary searches (key depends only on blockIdx.x)
    const int lo = lower_bound_dev(seg_ids, T, seg);
    const int hi = lower_bound_dev(seg_ids, T, seg + 1);

    const int d = threadIdx.x * 4;              // 256 threads * 4 floats = 1024 = D

    float4 acc = make_float4(0.f, 0.f, 0.f, 0.f);
    for (int t = lo; t < hi; ++t) {
        const int tok = tokens[t];              // uniform per block iteration
        const float4 v = *reinterpret_cast<const float4*>(emb + (size_t)tok * DD + d);
        acc.x += v.x; acc.y += v.y; acc.z += v.z; acc.w += v.w;
    }

    const int cnt = hi - lo;
    const float inv = (cnt > 0) ? (1.0f / (float)cnt) : 0.0f;

    const int s = seg & (SS - 1);               // seg % S
    const float4 p = *reinterpret_cast<const float4*>(pos + (size_t)s * DD + d);

    float4 o;
    o.x = acc.x * inv + p.x;
    o.y = acc.y * inv + p.y;
    o.z = acc.z * inv + p.z;
    o.w = acc.w * inv + p.w;

    *reinterpret_cast<float4*>(out + (size_t)seg * DD + d) = o;
}

extern "C" void kernel_launch(void* const* d_in, const int* in_sizes, int n_in,
                              void* d_out, int out_size, void* d_ws, size_t ws_size,
                              hipStream_t stream) {
    const int*   tokens  = (const int*)d_in[0];
    const int*   seg_ids = (const int*)d_in[1];
    const float* emb     = (const float*)d_in[2];
    const float* pos     = (const float*)d_in[3];
    float*       out     = (float*)d_out;
    const int T = in_sizes[0];

    seg_mean_embed_kernel<<<NSEG, 256, 0, stream>>>(tokens, seg_ids, emb, pos, out, T);
}

// Round 3
// 40.786 us; speedup vs baseline: 2.5897x; 2.5897x over previous
//
#include <hip/hip_runtime.h>
#include <hip/hip_bf16.h>

// Problem constants (match reference setup_inputs)
#define BB 64
#define SS 512
#define DD 1024
#define NSEG (BB * SS)   // 32768

typedef float floatx4 __attribute__((ext_vector_type(4)));

// ---------- Pass A: materialize segment start offsets from sorted segment_ids ----------
// seg_start has NSEG+1 entries; seg_start[s] = index of first token with seg_id >= s.
// Thread t closes the gap (seg_ids[t-1], seg_ids[t]]; thread T-1 also fills the tail.
__global__ __launch_bounds__(256) void fill_bounds_kernel(
    const int* __restrict__ seg_ids,
    int* __restrict__ seg_start,
    int T)
{
    int t = blockIdx.x * blockDim.x + threadIdx.x;
    if (t >= T) return;
    int cur  = seg_ids[t];
    int prev = (t == 0) ? -1 : seg_ids[t - 1];
    for (int s = prev + 1; s <= cur; ++s) seg_start[s] = t;
    if (t == T - 1) {
        for (int s = cur + 1; s <= NSEG; ++s) seg_start[s] = T;
    }
}

// ---------- Pass B: segment mean + positional add ----------
__global__ __launch_bounds__(256) void seg_mean_embed_kernel(
    const int* __restrict__ tokens,
    const int* __restrict__ seg_start,  // [NSEG+1]
    const float* __restrict__ emb,      // [V, D]
    const float* __restrict__ pos,      // [S, D]
    float* __restrict__ out)            // [B*S, D]
{
    const int seg = blockIdx.x;                 // 0 .. NSEG-1
    // Uniform (blockIdx-only) loads -> scalar path, O(1) latency chain
    const int lo = seg_start[seg];
    const int hi = seg_start[seg + 1];

    const int d = threadIdx.x * 4;              // 256 threads * 4 floats = 1024 = D

    floatx4 acc = (floatx4)(0.f);
    for (int t = lo; t < hi; ++t) {
        const int tok = tokens[t];              // uniform per iteration
        const floatx4 v = *reinterpret_cast<const floatx4*>(emb + (size_t)tok * DD + d);
        acc += v;
    }

    const int cnt = hi - lo;
    const float inv = (cnt > 0) ? (1.0f / (float)cnt) : 0.0f;

    const int s = seg & (SS - 1);               // seg % S
    const floatx4 p = *reinterpret_cast<const floatx4*>(pos + (size_t)s * DD + d);

    floatx4 o = acc * inv + p;

    // Non-temporal: 134 MB streaming write, keep emb/pos resident in L2
    __builtin_nontemporal_store(o, reinterpret_cast<floatx4*>(out + (size_t)seg * DD + d));
}

// ---------- Fallback (ws too small): binary-search kernel ----------
__device__ __forceinline__ int lower_bound_dev(const int* __restrict__ a, int n, int key) {
    int lo = 0, hi = n;
    while (lo < hi) {
        int mid = (lo + hi) >> 1;
        if (a[mid] < key) lo = mid + 1; else hi = mid;
    }
    return lo;
}

__global__ __launch_bounds__(256) void seg_mean_embed_bsearch_kernel(
    const int* __restrict__ tokens,
    const int* __restrict__ seg_ids,
    const float* __restrict__ emb,
    const float* __restrict__ pos,
    float* __restrict__ out,
    int T)
{
    const int seg = blockIdx.x;
    const int lo = lower_bound_dev(seg_ids, T, seg);
    const int hi = lower_bound_dev(seg_ids, T, seg + 1);
    const int d = threadIdx.x * 4;

    floatx4 acc = (floatx4)(0.f);
    for (int t = lo; t < hi; ++t) {
        const int tok = tokens[t];
        const floatx4 v = *reinterpret_cast<const floatx4*>(emb + (size_t)tok * DD + d);
        acc += v;
    }
    const int cnt = hi - lo;
    const float inv = (cnt > 0) ? (1.0f / (float)cnt) : 0.0f;
    const int s = seg & (SS - 1);
    const floatx4 p = *reinterpret_cast<const floatx4*>(pos + (size_t)s * DD + d);
    floatx4 o = acc * inv + p;
    *reinterpret_cast<floatx4*>(out + (size_t)seg * DD + d) = o;
}

extern "C" void kernel_launch(void* const* d_in, const int* in_sizes, int n_in,
                              void* d_out, int out_size, void* d_ws, size_t ws_size,
                              hipStream_t stream) {
    const int*   tokens  = (const int*)d_in[0];
    const int*   seg_ids = (const int*)d_in[1];
    const float* emb     = (const float*)d_in[2];
    const float* pos     = (const float*)d_in[3];
    float*       out     = (float*)d_out;
    const int T = in_sizes[0];

    const size_t need = (size_t)(NSEG + 1) * sizeof(int);
    if (ws_size >= need) {
        int* seg_start = (int*)d_ws;
        fill_bounds_kernel<<<(T + 255) / 256, 256, 0, stream>>>(seg_ids, seg_start, T);
        seg_mean_embed_kernel<<<NSEG, 256, 0, stream>>>(tokens, seg_start, emb, pos, out);
    } else {
        seg_mean_embed_bsearch_kernel<<<NSEG, 256, 0, stream>>>(tokens, seg_ids, emb, pos, out, T);
    }
}